// Round 1
// baseline (329.928 us; speedup 1.0000x reference)
//
#include <hip/hip_runtime.h>
#include <hip/hip_bf16.h>

#define B_   2
#define S_   2048
#define H_   16
#define D_   64
#define DIM_ 1024

typedef __attribute__((ext_vector_type(8))) short bf16x8;
typedef __attribute__((ext_vector_type(4))) float f32x4;
typedef unsigned short u16;

static __device__ __forceinline__ u16 f2bf(float f) {
    union { float f; unsigned u; } v; v.f = f;
    unsigned u = v.u;
    unsigned r = (u + 0x7fffu + ((u >> 16) & 1u)) >> 16;
    return (u16)r;
}

// ---------------------------------------------------------------- LayerNorm
__global__ __launch_bounds__(256) void ln_kernel(
    const float* __restrict__ x, const float* __restrict__ g,
    const float* __restrict__ b, u16* __restrict__ hb)
{
    int row = blockIdx.x;
    int t = threadIdx.x;
    const float4 v = ((const float4*)(x + row * DIM_))[t];
    float s  = v.x + v.y + v.z + v.w;
    float ss = v.x*v.x + v.y*v.y + v.z*v.z + v.w*v.w;
#pragma unroll
    for (int m = 1; m < 64; m <<= 1) { s += __shfl_xor(s, m); ss += __shfl_xor(ss, m); }
    __shared__ float rs[4], rss[4];
    int wid = t >> 6, lane = t & 63;
    if (lane == 0) { rs[wid] = s; rss[wid] = ss; }
    __syncthreads();
    s  = rs[0] + rs[1] + rs[2] + rs[3];
    ss = rss[0] + rss[1] + rss[2] + rss[3];
    float mu   = s * (1.0f / DIM_);
    float var  = ss * (1.0f / DIM_) - mu * mu;
    float rstd = rsqrtf(var + 1e-6f);
    const float4 gv = ((const float4*)g)[t];
    const float4 bv = ((const float4*)b)[t];
    ushort4 ov;
    ov.x = f2bf((v.x - mu) * rstd * gv.x + bv.x);
    ov.y = f2bf((v.y - mu) * rstd * gv.y + bv.y);
    ov.z = f2bf((v.z - mu) * rstd * gv.z + bv.z);
    ov.w = f2bf((v.w - mu) * rstd * gv.w + bv.w);
    ((ushort4*)(hb + row * DIM_))[t] = ov;
}

// ---------------------------------------------------------------- QKV GEMM
// A: h bf16 [4096][1024], W: fp32 [1024][3072], out: bf16 [3][32][2048][64]
__global__ __launch_bounds__(256) void qkv_gemm(
    const u16* __restrict__ A, const float* __restrict__ W,
    const float* __restrict__ bias, u16* __restrict__ qkv)
{
    __shared__ u16 As[64][48];
    __shared__ u16 Bt[64][48];
    int t = threadIdx.x;
    int bn = blockIdx.x * 64, bm = blockIdx.y * 64;
    int wid = t >> 6, lane = t & 63;
    int wr = wid >> 1, wc = wid & 1;
    int l15 = lane & 15, l4 = lane >> 4;

    f32x4 zero = {0.f, 0.f, 0.f, 0.f};
    f32x4 acc[2][2];
#pragma unroll
    for (int i = 0; i < 2; i++)
#pragma unroll
        for (int j = 0; j < 2; j++) acc[i][j] = zero;

    int ar = t >> 2, ac8 = (t & 3) * 8;   // A staging chunk
    int bk = t >> 3, bn8 = (t & 7) * 8;   // B staging chunk

    for (int k0 = 0; k0 < 1024; k0 += 32) {
        bf16x8 av = *(const bf16x8*)(A + (bm + ar) * 1024 + k0 + ac8);
        float4 w0 = *(const float4*)(W + (k0 + bk) * 3072 + bn + bn8);
        float4 w1 = *(const float4*)(W + (k0 + bk) * 3072 + bn + bn8 + 4);
        *(bf16x8*)&As[ar][ac8] = av;
        Bt[bn8 + 0][bk] = f2bf(w0.x); Bt[bn8 + 1][bk] = f2bf(w0.y);
        Bt[bn8 + 2][bk] = f2bf(w0.z); Bt[bn8 + 3][bk] = f2bf(w0.w);
        Bt[bn8 + 4][bk] = f2bf(w1.x); Bt[bn8 + 5][bk] = f2bf(w1.y);
        Bt[bn8 + 6][bk] = f2bf(w1.z); Bt[bn8 + 7][bk] = f2bf(w1.w);
        __syncthreads();
        bf16x8 a0 = *(const bf16x8*)&As[wr * 32 + l15][8 * l4];
        bf16x8 a1 = *(const bf16x8*)&As[wr * 32 + 16 + l15][8 * l4];
        bf16x8 b0 = *(const bf16x8*)&Bt[wc * 32 + l15][8 * l4];
        bf16x8 b1 = *(const bf16x8*)&Bt[wc * 32 + 16 + l15][8 * l4];
        acc[0][0] = __builtin_amdgcn_mfma_f32_16x16x32_bf16(a0, b0, acc[0][0], 0, 0, 0);
        acc[0][1] = __builtin_amdgcn_mfma_f32_16x16x32_bf16(a0, b1, acc[0][1], 0, 0, 0);
        acc[1][0] = __builtin_amdgcn_mfma_f32_16x16x32_bf16(a1, b0, acc[1][0], 0, 0, 0);
        acc[1][1] = __builtin_amdgcn_mfma_f32_16x16x32_bf16(a1, b1, acc[1][1], 0, 0, 0);
        __syncthreads();
    }
#pragma unroll
    for (int mi = 0; mi < 2; mi++)
#pragma unroll
        for (int ni = 0; ni < 2; ni++) {
            int col = bn + wc * 32 + ni * 16 + l15;
            int which = col >> 10, f = col & 1023;
            int hh = f >> 6, d = f & 63;
            float bs = bias[col];
#pragma unroll
            for (int r = 0; r < 4; r++) {
                int row = bm + wr * 32 + mi * 16 + l4 * 4 + r;
                int bb = row >> 11, s = row & 2047;
                qkv[which * (32 * 2048 * 64) + ((bb * 16 + hh) * 2048 + s) * 64 + d] =
                    f2bf(acc[mi][ni][r] + bs);
            }
        }
}

// ---------------------------------------------------------------- Flash attention
// q,k,v: bf16 [32][2048][64]; ctx out: bf16 [4096][1024] (b,s, h*64+d)
__global__ __launch_bounds__(256) void attn_kernel(
    const u16* __restrict__ qbuf, const u16* __restrict__ kbuf,
    const u16* __restrict__ vbuf, u16* __restrict__ ctx)
{
    __shared__ u16 Ks[64][72];
    __shared__ u16 Vt[64][72];
    __shared__ u16 Pl[4][16][72];
    int t = threadIdx.x, wid = t >> 6, lane = t & 63;
    int l15 = lane & 15, l4 = lane >> 4;
    int qt = blockIdx.x, bh = blockIdx.y;
    int q0 = qt * 64;

    const u16* Q = qbuf + (bh * 2048 + q0 + wid * 16) * 64;
    bf16x8 aq0 = *(const bf16x8*)(Q + l15 * 64 + 8 * l4);
    bf16x8 aq1 = *(const bf16x8*)(Q + l15 * 64 + 32 + 8 * l4);

    f32x4 zero = {0.f, 0.f, 0.f, 0.f};
    f32x4 o[4];
#pragma unroll
    for (int f = 0; f < 4; f++) o[f] = zero;
    float m_run[4] = {-1e30f, -1e30f, -1e30f, -1e30f};
    float l_run[4] = {0.f, 0.f, 0.f, 0.f};

    int sr = t >> 3, sd8 = (t & 7) * 8;   // staging: row, d-offset

    for (int kt = 0; kt <= qt; ++kt) {
        int k0 = kt * 64;
        const u16* Kb = kbuf + (bh * 2048 + k0) * 64;
        const u16* Vb = vbuf + (bh * 2048 + k0) * 64;
        bf16x8 kv0 = *(const bf16x8*)(Kb + sr * 64 + sd8);
        bf16x8 kv1 = *(const bf16x8*)(Kb + (sr + 32) * 64 + sd8);
        bf16x8 vv0 = *(const bf16x8*)(Vb + sr * 64 + sd8);
        bf16x8 vv1 = *(const bf16x8*)(Vb + (sr + 32) * 64 + sd8);
        *(bf16x8*)&Ks[sr][sd8] = kv0;
        *(bf16x8*)&Ks[sr + 32][sd8] = kv1;
#pragma unroll
        for (int i = 0; i < 8; i++) { Vt[sd8 + i][sr] = vv0[i]; Vt[sd8 + i][sr + 32] = vv1[i]; }
        __syncthreads();

        // scores: Q @ K^T
        f32x4 sc[4];
#pragma unroll
        for (int nf = 0; nf < 4; ++nf) {
            bf16x8 kb0 = *(const bf16x8*)&Ks[nf * 16 + l15][8 * l4];
            bf16x8 kb1 = *(const bf16x8*)&Ks[nf * 16 + l15][32 + 8 * l4];
            f32x4 z = zero;
            z = __builtin_amdgcn_mfma_f32_16x16x32_bf16(aq0, kb0, z, 0, 0, 0);
            z = __builtin_amdgcn_mfma_f32_16x16x32_bf16(aq1, kb1, z, 0, 0, 0);
            sc[nf] = z;
        }
        bool diag = (kt == qt);
#pragma unroll
        for (int nf = 0; nf < 4; nf++)
#pragma unroll
            for (int r = 0; r < 4; r++) {
                float v = sc[nf][r] * 0.125f;
                if (diag) {
                    int qa = wid * 16 + l4 * 4 + r;
                    int ka = nf * 16 + l15;
                    if (ka > qa) v = -1e30f;
                }
                sc[nf][r] = v;
            }
        // online softmax
        float alpha[4];
#pragma unroll
        for (int r = 0; r < 4; r++) {
            float mx = fmaxf(fmaxf(sc[0][r], sc[1][r]), fmaxf(sc[2][r], sc[3][r]));
#pragma unroll
            for (int m = 1; m < 16; m <<= 1) mx = fmaxf(mx, __shfl_xor(mx, m));
            float mn = fmaxf(m_run[r], mx);
            alpha[r] = __expf(m_run[r] - mn);
            float rsum = 0.f;
#pragma unroll
            for (int nf = 0; nf < 4; nf++) {
                float p = __expf(sc[nf][r] - mn);
                sc[nf][r] = p; rsum += p;
            }
#pragma unroll
            for (int m = 1; m < 16; m <<= 1) rsum += __shfl_xor(rsum, m);
            l_run[r] = l_run[r] * alpha[r] + rsum;
            m_run[r] = mn;
        }
#pragma unroll
        for (int f = 0; f < 4; f++)
#pragma unroll
            for (int r = 0; r < 4; r++) o[f][r] *= alpha[r];
        // P -> LDS (wave-private)
#pragma unroll
        for (int nf = 0; nf < 4; nf++)
#pragma unroll
            for (int r = 0; r < 4; r++)
                Pl[wid][l4 * 4 + r][nf * 16 + l15] = f2bf(sc[nf][r]);
        // P @ V
#pragma unroll
        for (int kk = 0; kk < 2; kk++) {
            bf16x8 pa = *(const bf16x8*)&Pl[wid][l15][kk * 32 + 8 * l4];
#pragma unroll
            for (int f = 0; f < 4; f++) {
                bf16x8 vb = *(const bf16x8*)&Vt[f * 16 + l15][kk * 32 + 8 * l4];
                o[f] = __builtin_amdgcn_mfma_f32_16x16x32_bf16(pa, vb, o[f], 0, 0, 0);
            }
        }
        __syncthreads();
    }
    int bb = bh >> 4, hh = bh & 15;
#pragma unroll
    for (int r = 0; r < 4; r++) {
        float inv = 1.f / l_run[r];
        int qa = q0 + wid * 16 + l4 * 4 + r;
        u16* dst = ctx + (bb * 2048 + qa) * 1024 + hh * 64;
#pragma unroll
        for (int f = 0; f < 4; f++) dst[f * 16 + l15] = f2bf(o[f][r] * inv);
    }
}

// ---------------------------------------------------------------- Out GEMM + residual
// A: ctx bf16 [4096][1024], W: wo fp32 [1024][1024], out: fp32 [4096][1024]
__global__ __launch_bounds__(256) void out_gemm(
    const u16* __restrict__ A, const float* __restrict__ W,
    const float* __restrict__ bias, const float* __restrict__ xres,
    float* __restrict__ out)
{
    __shared__ u16 As[64][48];
    __shared__ u16 Bt[64][48];
    int t = threadIdx.x;
    int bn = blockIdx.x * 64, bm = blockIdx.y * 64;
    int wid = t >> 6, lane = t & 63;
    int wr = wid >> 1, wc = wid & 1;
    int l15 = lane & 15, l4 = lane >> 4;

    f32x4 zero = {0.f, 0.f, 0.f, 0.f};
    f32x4 acc[2][2];
#pragma unroll
    for (int i = 0; i < 2; i++)
#pragma unroll
        for (int j = 0; j < 2; j++) acc[i][j] = zero;

    int ar = t >> 2, ac8 = (t & 3) * 8;
    int bk = t >> 3, bn8 = (t & 7) * 8;

    for (int k0 = 0; k0 < 1024; k0 += 32) {
        bf16x8 av = *(const bf16x8*)(A + (bm + ar) * 1024 + k0 + ac8);
        float4 w0 = *(const float4*)(W + (k0 + bk) * 1024 + bn + bn8);
        float4 w1 = *(const float4*)(W + (k0 + bk) * 1024 + bn + bn8 + 4);
        *(bf16x8*)&As[ar][ac8] = av;
        Bt[bn8 + 0][bk] = f2bf(w0.x); Bt[bn8 + 1][bk] = f2bf(w0.y);
        Bt[bn8 + 2][bk] = f2bf(w0.z); Bt[bn8 + 3][bk] = f2bf(w0.w);
        Bt[bn8 + 4][bk] = f2bf(w1.x); Bt[bn8 + 5][bk] = f2bf(w1.y);
        Bt[bn8 + 6][bk] = f2bf(w1.z); Bt[bn8 + 7][bk] = f2bf(w1.w);
        __syncthreads();
        bf16x8 a0 = *(const bf16x8*)&As[wr * 32 + l15][8 * l4];
        bf16x8 a1 = *(const bf16x8*)&As[wr * 32 + 16 + l15][8 * l4];
        bf16x8 b0 = *(const bf16x8*)&Bt[wc * 32 + l15][8 * l4];
        bf16x8 b1 = *(const bf16x8*)&Bt[wc * 32 + 16 + l15][8 * l4];
        acc[0][0] = __builtin_amdgcn_mfma_f32_16x16x32_bf16(a0, b0, acc[0][0], 0, 0, 0);
        acc[0][1] = __builtin_amdgcn_mfma_f32_16x16x32_bf16(a0, b1, acc[0][1], 0, 0, 0);
        acc[1][0] = __builtin_amdgcn_mfma_f32_16x16x32_bf16(a1, b0, acc[1][0], 0, 0, 0);
        acc[1][1] = __builtin_amdgcn_mfma_f32_16x16x32_bf16(a1, b1, acc[1][1], 0, 0, 0);
        __syncthreads();
    }
#pragma unroll
    for (int mi = 0; mi < 2; mi++)
#pragma unroll
        for (int ni = 0; ni < 2; ni++) {
            int col = bn + wc * 32 + ni * 16 + l15;
            float bs = bias[col];
#pragma unroll
            for (int r = 0; r < 4; r++) {
                int row = bm + wr * 32 + mi * 16 + l4 * 4 + r;
                out[row * 1024 + col] = xres[row * 1024 + col] + acc[mi][ni][r] + bs;
            }
        }
}

// ----------------------------------------------------------------
extern "C" void kernel_launch(void* const* d_in, const int* in_sizes, int n_in,
                              void* d_out, int out_size, void* d_ws, size_t ws_size,
                              hipStream_t stream)
{
    const float* x    = (const float*)d_in[0];
    const float* ln_g = (const float*)d_in[1];
    const float* ln_b = (const float*)d_in[2];
    const float* wqkv = (const float*)d_in[3];
    const float* bqkv = (const float*)d_in[4];
    const float* wo   = (const float*)d_in[5];
    const float* bo   = (const float*)d_in[6];
    float* out = (float*)d_out;

    char* ws = (char*)d_ws;
    u16* hbuf = (u16*)ws;                              // 4096*1024*2       =  8 MB
    u16* qkvb = (u16*)(ws + 8388608);                  // 3*32*2048*64*2    = 25 MB
    u16* ctxb = (u16*)(ws + 8388608 + 25165824);       // 4096*1024*2       =  8 MB

    ln_kernel<<<4096, 256, 0, stream>>>(x, ln_g, ln_b, hbuf);
    qkv_gemm<<<dim3(48, 64), 256, 0, stream>>>(hbuf, wqkv, bqkv, qkvb);
    attn_kernel<<<dim3(32, 32), 256, 0, stream>>>(
        qkvb, qkvb + 32 * 2048 * 64, qkvb + 2 * 32 * 2048 * 64, ctxb);
    out_gemm<<<dim3(16, 64), 256, 0, stream>>>(ctxb, wo, bo, x, out);
}

// Round 3
// 189.605 us; speedup vs baseline: 1.7401x; 1.7401x over previous
//
#include <hip/hip_runtime.h>
#include <hip/hip_bf16.h>

#define B_   2
#define S_   2048
#define H_   16
#define D_   64
#define DIM_ 1024

typedef __attribute__((ext_vector_type(8))) short bf16x8;
typedef __attribute__((ext_vector_type(4))) float f32x4;
typedef unsigned short u16;

static __device__ __forceinline__ u16 f2bf(float f) {
    union { float f; unsigned u; } v; v.f = f;
    unsigned u = v.u;
    unsigned r = (u + 0x7fffu + ((u >> 16) & 1u)) >> 16;
    return (u16)r;
}

static __device__ __forceinline__ void gload_lds16(const u16* g, u16* l) {
    __builtin_amdgcn_global_load_lds(
        (const __attribute__((address_space(1))) void*)g,
        (__attribute__((address_space(3))) void*)l, 16, 0, 0);
}

// ---------------------------------------------------------------- LayerNorm
__global__ __launch_bounds__(256) void ln_kernel(
    const float* __restrict__ x, const float* __restrict__ g,
    const float* __restrict__ b, u16* __restrict__ hb)
{
    int row = blockIdx.x;
    int t = threadIdx.x;
    const float4 v = ((const float4*)(x + row * DIM_))[t];
    float s  = v.x + v.y + v.z + v.w;
    float ss = v.x*v.x + v.y*v.y + v.z*v.z + v.w*v.w;
#pragma unroll
    for (int m = 1; m < 64; m <<= 1) { s += __shfl_xor(s, m); ss += __shfl_xor(ss, m); }
    __shared__ float rs[4], rss[4];
    int wid = t >> 6, lane = t & 63;
    if (lane == 0) { rs[wid] = s; rss[wid] = ss; }
    __syncthreads();
    s  = rs[0] + rs[1] + rs[2] + rs[3];
    ss = rss[0] + rss[1] + rss[2] + rss[3];
    float mu   = s * (1.0f / DIM_);
    float var  = ss * (1.0f / DIM_) - mu * mu;
    float rstd = rsqrtf(var + 1e-6f);
    const float4 gv = ((const float4*)g)[t];
    const float4 bv = ((const float4*)b)[t];
    ushort4 ov;
    ov.x = f2bf((v.x - mu) * rstd * gv.x + bv.x);
    ov.y = f2bf((v.y - mu) * rstd * gv.y + bv.y);
    ov.z = f2bf((v.z - mu) * rstd * gv.z + bv.z);
    ov.w = f2bf((v.w - mu) * rstd * gv.w + bv.w);
    ((ushort4*)(hb + row * DIM_))[t] = ov;
}

// ---------------------------------------------------------------- fp32 -> bf16 transpose
// src [R][C] f32  ->  dst [C][R] bf16
__global__ __launch_bounds__(256) void transpose_f32_bf16(
    const float* __restrict__ src, u16* __restrict__ dst, int R, int C)
{
    __shared__ u16 T[64][65];
    int c0 = blockIdx.x * 64, r0 = blockIdx.y * 64;
    int t = threadIdx.x;
    int rl = t >> 4, cl = (t & 15) * 4;
#pragma unroll
    for (int p = 0; p < 4; p++) {
        float4 v = *(const float4*)(src + (size_t)(r0 + rl + p * 16) * C + c0 + cl);
        T[cl + 0][rl + p * 16] = f2bf(v.x);
        T[cl + 1][rl + p * 16] = f2bf(v.y);
        T[cl + 2][rl + p * 16] = f2bf(v.z);
        T[cl + 3][rl + p * 16] = f2bf(v.w);
    }
    __syncthreads();
#pragma unroll
    for (int p = 0; p < 4; p++) {
        ushort4 o;
        o.x = T[rl + p * 16][cl + 0];
        o.y = T[rl + p * 16][cl + 1];
        o.z = T[rl + p * 16][cl + 2];
        o.w = T[rl + p * 16][cl + 3];
        *(ushort4*)(dst + (size_t)(c0 + rl + p * 16) * R + r0 + cl) = o;
    }
}

// ---------------------------------------------------------------- QKV GEMM 128x128
// A: bf16 [4096][1024], Bw: bf16 [3072][1024] (W^T), out: bf16 [3][32][2048][64]
__global__ __launch_bounds__(256) void qkv_gemm128(
    const u16* __restrict__ A, const u16* __restrict__ Bw,
    const float* __restrict__ bias, u16* __restrict__ qkv)
{
    __shared__ __align__(16) u16 As[128 * 32];
    __shared__ __align__(16) u16 Bs[128 * 32];
    int t = threadIdx.x;
    int bn = blockIdx.x * 128, bm = blockIdx.y * 128;
    int wid = t >> 6, lane = t & 63;
    int wm = wid >> 1, wn = wid & 1;
    int l15 = lane & 15, l4 = lane >> 4;

    f32x4 zero = {0.f, 0.f, 0.f, 0.f};
    f32x4 acc[4][4];
#pragma unroll
    for (int i = 0; i < 4; i++)
#pragma unroll
        for (int j = 0; j < 4; j++) acc[i][j] = zero;

    const u16* aSrc = A  + (size_t)(bm + wid * 32 + (lane >> 2)) * 1024 + (lane & 3) * 8;
    const u16* bSrc = Bw + (size_t)(bn + wid * 32 + (lane >> 2)) * 1024 + (lane & 3) * 8;
    char* AsB = (char*)As + wid * 2048;
    char* BsB = (char*)Bs + wid * 2048;

    for (int k0 = 0; k0 < 1024; k0 += 32) {
        gload_lds16(aSrc + k0,             (u16*)(AsB));
        gload_lds16(aSrc + k0 + 16 * 1024, (u16*)(AsB + 1024));
        gload_lds16(bSrc + k0,             (u16*)(BsB));
        gload_lds16(bSrc + k0 + 16 * 1024, (u16*)(BsB + 1024));
        __syncthreads();
        bf16x8 af[4], bf[4];
#pragma unroll
        for (int mi = 0; mi < 4; mi++)
            af[mi] = *(const bf16x8*)((char*)As + (wm * 64 + mi * 16 + l15) * 64 + l4 * 16);
#pragma unroll
        for (int ni = 0; ni < 4; ni++)
            bf[ni] = *(const bf16x8*)((char*)Bs + (wn * 64 + ni * 16 + l15) * 64 + l4 * 16);
#pragma unroll
        for (int mi = 0; mi < 4; mi++)
#pragma unroll
            for (int ni = 0; ni < 4; ni++)
                acc[mi][ni] = __builtin_amdgcn_mfma_f32_16x16x32_bf16(af[mi], bf[ni], acc[mi][ni], 0, 0, 0);
        __syncthreads();
    }
#pragma unroll
    for (int mi = 0; mi < 4; mi++)
#pragma unroll
        for (int ni = 0; ni < 4; ni++) {
            int col = bn + wn * 64 + ni * 16 + l15;
            int which = col >> 10, f = col & 1023;
            int hh = f >> 6, d = f & 63;
            float bs = bias[col];
#pragma unroll
            for (int r = 0; r < 4; r++) {
                int row = bm + wm * 64 + mi * 16 + l4 * 4 + r;
                int bb = row >> 11, s = row & 2047;
                qkv[(size_t)which * (32 * 2048 * 64) + ((size_t)(bb * 16 + hh) * 2048 + s) * 64 + d] =
                    f2bf(acc[mi][ni][r] + bs);
            }
        }
}

// ---------------------------------------------------------------- Out GEMM 128x128 + residual
__global__ __launch_bounds__(256) void out_gemm128(
    const u16* __restrict__ A, const u16* __restrict__ Bw,
    const float* __restrict__ bias, const float* __restrict__ xres,
    float* __restrict__ out)
{
    __shared__ __align__(16) u16 As[128 * 32];
    __shared__ __align__(16) u16 Bs[128 * 32];
    int t = threadIdx.x;
    int bn = blockIdx.x * 128, bm = blockIdx.y * 128;
    int wid = t >> 6, lane = t & 63;
    int wm = wid >> 1, wn = wid & 1;
    int l15 = lane & 15, l4 = lane >> 4;

    f32x4 zero = {0.f, 0.f, 0.f, 0.f};
    f32x4 acc[4][4];
#pragma unroll
    for (int i = 0; i < 4; i++)
#pragma unroll
        for (int j = 0; j < 4; j++) acc[i][j] = zero;

    const u16* aSrc = A  + (size_t)(bm + wid * 32 + (lane >> 2)) * 1024 + (lane & 3) * 8;
    const u16* bSrc = Bw + (size_t)(bn + wid * 32 + (lane >> 2)) * 1024 + (lane & 3) * 8;
    char* AsB = (char*)As + wid * 2048;
    char* BsB = (char*)Bs + wid * 2048;

    for (int k0 = 0; k0 < 1024; k0 += 32) {
        gload_lds16(aSrc + k0,             (u16*)(AsB));
        gload_lds16(aSrc + k0 + 16 * 1024, (u16*)(AsB + 1024));
        gload_lds16(bSrc + k0,             (u16*)(BsB));
        gload_lds16(bSrc + k0 + 16 * 1024, (u16*)(BsB + 1024));
        __syncthreads();
        bf16x8 af[4], bf[4];
#pragma unroll
        for (int mi = 0; mi < 4; mi++)
            af[mi] = *(const bf16x8*)((char*)As + (wm * 64 + mi * 16 + l15) * 64 + l4 * 16);
#pragma unroll
        for (int ni = 0; ni < 4; ni++)
            bf[ni] = *(const bf16x8*)((char*)Bs + (wn * 64 + ni * 16 + l15) * 64 + l4 * 16);
#pragma unroll
        for (int mi = 0; mi < 4; mi++)
#pragma unroll
            for (int ni = 0; ni < 4; ni++)
                acc[mi][ni] = __builtin_amdgcn_mfma_f32_16x16x32_bf16(af[mi], bf[ni], acc[mi][ni], 0, 0, 0);
        __syncthreads();
    }
#pragma unroll
    for (int mi = 0; mi < 4; mi++)
#pragma unroll
        for (int ni = 0; ni < 4; ni++) {
            int col = bn + wn * 64 + ni * 16 + l15;
            float bs = bias[col];
#pragma unroll
            for (int r = 0; r < 4; r++) {
                int row = bm + wm * 64 + mi * 16 + l4 * 4 + r;
                out[(size_t)row * 1024 + col] = xres[(size_t)row * 1024 + col] + acc[mi][ni][r] + bs;
            }
        }
}

// ---------------------------------------------------------------- Flash attention
// Round-1-proven body + q-tile pairing (qt = p, then 31-p) for load balance.
__global__ __launch_bounds__(256) void attn_kernel(
    const u16* __restrict__ qbuf, const u16* __restrict__ kbuf,
    const u16* __restrict__ vbuf, u16* __restrict__ ctx)
{
    __shared__ u16 Ks[64][72];
    __shared__ u16 Vt[64][72];
    __shared__ u16 Pl[4][16][72];
    int t = threadIdx.x, wid = t >> 6, lane = t & 63;
    int l15 = lane & 15, l4 = lane >> 4;
    int p = blockIdx.x, bh = blockIdx.y;
    int sr = t >> 3, sd8 = (t & 7) * 8;   // staging: row, d-offset
    int bb = bh >> 4, hh = bh & 15;
    f32x4 zero = {0.f, 0.f, 0.f, 0.f};

    for (int pass = 0; pass < 2; ++pass) {
        int qt = pass ? (31 - p) : p;
        int q0 = qt * 64;

        const u16* Q = qbuf + (size_t)(bh * 2048 + q0 + wid * 16) * 64;
        bf16x8 aq0 = *(const bf16x8*)(Q + l15 * 64 + 8 * l4);
        bf16x8 aq1 = *(const bf16x8*)(Q + l15 * 64 + 32 + 8 * l4);

        f32x4 o[4];
#pragma unroll
        for (int f = 0; f < 4; f++) o[f] = zero;
        float m_run[4] = {-1e30f, -1e30f, -1e30f, -1e30f};
        float l_run[4] = {0.f, 0.f, 0.f, 0.f};

        for (int kt = 0; kt <= qt; ++kt) {
            int k0 = kt * 64;
            const u16* Kb = kbuf + (size_t)(bh * 2048 + k0) * 64;
            const u16* Vb = vbuf + (size_t)(bh * 2048 + k0) * 64;
            bf16x8 kv0 = *(const bf16x8*)(Kb + sr * 64 + sd8);
            bf16x8 kv1 = *(const bf16x8*)(Kb + (sr + 32) * 64 + sd8);
            bf16x8 vv0 = *(const bf16x8*)(Vb + sr * 64 + sd8);
            bf16x8 vv1 = *(const bf16x8*)(Vb + (sr + 32) * 64 + sd8);
            *(bf16x8*)&Ks[sr][sd8] = kv0;
            *(bf16x8*)&Ks[sr + 32][sd8] = kv1;
#pragma unroll
            for (int i = 0; i < 8; i++) { Vt[sd8 + i][sr] = vv0[i]; Vt[sd8 + i][sr + 32] = vv1[i]; }
            __syncthreads();

            // scores: Q @ K^T
            f32x4 sc[4];
#pragma unroll
            for (int nf = 0; nf < 4; ++nf) {
                bf16x8 kb0 = *(const bf16x8*)&Ks[nf * 16 + l15][8 * l4];
                bf16x8 kb1 = *(const bf16x8*)&Ks[nf * 16 + l15][32 + 8 * l4];
                f32x4 z = zero;
                z = __builtin_amdgcn_mfma_f32_16x16x32_bf16(aq0, kb0, z, 0, 0, 0);
                z = __builtin_amdgcn_mfma_f32_16x16x32_bf16(aq1, kb1, z, 0, 0, 0);
                sc[nf] = z;
            }
            bool diag = (kt == qt);
#pragma unroll
            for (int nf = 0; nf < 4; nf++)
#pragma unroll
                for (int r = 0; r < 4; r++) {
                    float v = sc[nf][r] * 0.125f;
                    if (diag) {
                        int qa = wid * 16 + l4 * 4 + r;
                        int ka = nf * 16 + l15;
                        if (ka > qa) v = -1e30f;
                    }
                    sc[nf][r] = v;
                }
            // online softmax
            float alpha[4];
#pragma unroll
            for (int r = 0; r < 4; r++) {
                float mx = fmaxf(fmaxf(sc[0][r], sc[1][r]), fmaxf(sc[2][r], sc[3][r]));
#pragma unroll
                for (int m = 1; m < 16; m <<= 1) mx = fmaxf(mx, __shfl_xor(mx, m));
                float mn = fmaxf(m_run[r], mx);
                alpha[r] = __expf(m_run[r] - mn);
                float rsum = 0.f;
#pragma unroll
                for (int nf = 0; nf < 4; nf++) {
                    float pv = __expf(sc[nf][r] - mn);
                    sc[nf][r] = pv; rsum += pv;
                }
#pragma unroll
                for (int m = 1; m < 16; m <<= 1) rsum += __shfl_xor(rsum, m);
                l_run[r] = l_run[r] * alpha[r] + rsum;
                m_run[r] = mn;
            }
#pragma unroll
            for (int f = 0; f < 4; f++)
#pragma unroll
                for (int r = 0; r < 4; r++) o[f][r] *= alpha[r];
            // P -> LDS (wave-private)
#pragma unroll
            for (int nf = 0; nf < 4; nf++)
#pragma unroll
                for (int r = 0; r < 4; r++)
                    Pl[wid][l4 * 4 + r][nf * 16 + l15] = f2bf(sc[nf][r]);
            // P @ V
#pragma unroll
            for (int kk = 0; kk < 2; kk++) {
                bf16x8 pa = *(const bf16x8*)&Pl[wid][l15][kk * 32 + 8 * l4];
#pragma unroll
                for (int f = 0; f < 4; f++) {
                    bf16x8 vb = *(const bf16x8*)&Vt[f * 16 + l15][kk * 32 + 8 * l4];
                    o[f] = __builtin_amdgcn_mfma_f32_16x16x32_bf16(pa, vb, o[f], 0, 0, 0);
                }
            }
            __syncthreads();
        }
        // output
#pragma unroll
        for (int r = 0; r < 4; r++) {
            float inv = 1.f / l_run[r];
            int qa = q0 + wid * 16 + l4 * 4 + r;
            u16* dst = ctx + (size_t)(bb * 2048 + qa) * 1024 + hh * 64;
#pragma unroll
            for (int f = 0; f < 4; f++) dst[f * 16 + l15] = f2bf(o[f][r] * inv);
        }
    }
}

// ----------------------------------------------------------------
extern "C" void kernel_launch(void* const* d_in, const int* in_sizes, int n_in,
                              void* d_out, int out_size, void* d_ws, size_t ws_size,
                              hipStream_t stream)
{
    const float* x    = (const float*)d_in[0];
    const float* ln_g = (const float*)d_in[1];
    const float* ln_b = (const float*)d_in[2];
    const float* wqkv = (const float*)d_in[3];
    const float* bqkv = (const float*)d_in[4];
    const float* wo   = (const float*)d_in[5];
    const float* bo   = (const float*)d_in[6];
    float* out = (float*)d_out;

    char* ws = (char*)d_ws;
    u16* hbuf  = (u16*)ws;                          // 8 MB   (LN out; later woT reuses front)
    u16* qkvb  = (u16*)(ws + 8388608);              // 24 MB  qkv head-major
    u16* ctxb  = (u16*)(ws + 33554432);             // 8 MB   (wqkvT first, then ctx)
    u16* wqkvT = ctxb;                              // 6.29 MB (dead before attn writes ctx)
    u16* woT   = hbuf;                              // 2 MB   (hbuf dead after qkv_gemm)

    transpose_f32_bf16<<<dim3(48, 16), 256, 0, stream>>>(wqkv, wqkvT, 1024, 3072);
    ln_kernel<<<4096, 256, 0, stream>>>(x, ln_g, ln_b, hbuf);
    qkv_gemm128<<<dim3(24, 32), 256, 0, stream>>>(hbuf, wqkvT, bqkv, qkvb);
    transpose_f32_bf16<<<dim3(16, 16), 256, 0, stream>>>(wo, woT, 1024, 1024);
    attn_kernel<<<dim3(16, 32), 256, 0, stream>>>(
        qkvb, qkvb + 32 * 2048 * 64, qkvb + 2 * 32 * 2048 * 64, ctxb);
    out_gemm128<<<dim3(8, 32), 256, 0, stream>>>(ctxb, woT, bo, x, out);
}

// Round 4
// 158.772 us; speedup vs baseline: 2.0780x; 1.1942x over previous
//
#include <hip/hip_runtime.h>
#include <hip/hip_bf16.h>

#define B_   2
#define S_   2048
#define H_   16
#define D_   64
#define DIM_ 1024

typedef __attribute__((ext_vector_type(8))) short bf16x8;
typedef __attribute__((ext_vector_type(4))) float f32x4;
typedef unsigned short u16;

static __device__ __forceinline__ u16 f2bf(float f) {
    union { float f; unsigned u; } v; v.f = f;
    unsigned u = v.u;
    unsigned r = (u + 0x7fffu + ((u >> 16) & 1u)) >> 16;
    return (u16)r;
}

static __device__ __forceinline__ void gload_lds16(const u16* g, u16* l) {
    __builtin_amdgcn_global_load_lds(
        (const __attribute__((address_space(1))) void*)g,
        (__attribute__((address_space(3))) void*)l, 16, 0, 0);
}

// ---------------------------------------------------------------- LayerNorm
__global__ __launch_bounds__(256) void ln_kernel(
    const float* __restrict__ x, const float* __restrict__ g,
    const float* __restrict__ b, u16* __restrict__ hb)
{
    int row = blockIdx.x;
    int t = threadIdx.x;
    const float4 v = ((const float4*)(x + row * DIM_))[t];
    float s  = v.x + v.y + v.z + v.w;
    float ss = v.x*v.x + v.y*v.y + v.z*v.z + v.w*v.w;
#pragma unroll
    for (int m = 1; m < 64; m <<= 1) { s += __shfl_xor(s, m); ss += __shfl_xor(ss, m); }
    __shared__ float rs[4], rss[4];
    int wid = t >> 6, lane = t & 63;
    if (lane == 0) { rs[wid] = s; rss[wid] = ss; }
    __syncthreads();
    s  = rs[0] + rs[1] + rs[2] + rs[3];
    ss = rss[0] + rss[1] + rss[2] + rss[3];
    float mu   = s * (1.0f / DIM_);
    float var  = ss * (1.0f / DIM_) - mu * mu;
    float rstd = rsqrtf(var + 1e-6f);
    const float4 gv = ((const float4*)g)[t];
    const float4 bv = ((const float4*)b)[t];
    ushort4 ov;
    ov.x = f2bf((v.x - mu) * rstd * gv.x + bv.x);
    ov.y = f2bf((v.y - mu) * rstd * gv.y + bv.y);
    ov.z = f2bf((v.z - mu) * rstd * gv.z + bv.z);
    ov.w = f2bf((v.w - mu) * rstd * gv.w + bv.w);
    ((ushort4*)(hb + row * DIM_))[t] = ov;
}

// ---------------------------------------------------------------- fp32 -> bf16 transpose
__global__ __launch_bounds__(256) void transpose_f32_bf16(
    const float* __restrict__ src, u16* __restrict__ dst, int R, int C)
{
    __shared__ u16 T[64][65];
    int c0 = blockIdx.x * 64, r0 = blockIdx.y * 64;
    int t = threadIdx.x;
    int rl = t >> 4, cl = (t & 15) * 4;
#pragma unroll
    for (int p = 0; p < 4; p++) {
        float4 v = *(const float4*)(src + (size_t)(r0 + rl + p * 16) * C + c0 + cl);
        T[cl + 0][rl + p * 16] = f2bf(v.x);
        T[cl + 1][rl + p * 16] = f2bf(v.y);
        T[cl + 2][rl + p * 16] = f2bf(v.z);
        T[cl + 3][rl + p * 16] = f2bf(v.w);
    }
    __syncthreads();
#pragma unroll
    for (int p = 0; p < 4; p++) {
        ushort4 o;
        o.x = T[rl + p * 16][cl + 0];
        o.y = T[rl + p * 16][cl + 1];
        o.z = T[rl + p * 16][cl + 2];
        o.w = T[rl + p * 16][cl + 3];
        *(ushort4*)(dst + (size_t)(c0 + rl + p * 16) * R + r0 + cl) = o;
    }
}

// ---------------------------------------------------------------- QKV GEMM 128x128
__global__ __launch_bounds__(256) void qkv_gemm128(
    const u16* __restrict__ A, const u16* __restrict__ Bw,
    const float* __restrict__ bias, u16* __restrict__ qkv)
{
    __shared__ __align__(16) u16 As[128 * 32];
    __shared__ __align__(16) u16 Bs[128 * 32];
    int t = threadIdx.x;
    int bn = blockIdx.x * 128, bm = blockIdx.y * 128;
    int wid = t >> 6, lane = t & 63;
    int wm = wid >> 1, wn = wid & 1;
    int l15 = lane & 15, l4 = lane >> 4;

    f32x4 zero = {0.f, 0.f, 0.f, 0.f};
    f32x4 acc[4][4];
#pragma unroll
    for (int i = 0; i < 4; i++)
#pragma unroll
        for (int j = 0; j < 4; j++) acc[i][j] = zero;

    const u16* aSrc = A  + (size_t)(bm + wid * 32 + (lane >> 2)) * 1024 + (lane & 3) * 8;
    const u16* bSrc = Bw + (size_t)(bn + wid * 32 + (lane >> 2)) * 1024 + (lane & 3) * 8;
    char* AsB = (char*)As + wid * 2048;
    char* BsB = (char*)Bs + wid * 2048;

    for (int k0 = 0; k0 < 1024; k0 += 32) {
        gload_lds16(aSrc + k0,             (u16*)(AsB));
        gload_lds16(aSrc + k0 + 16 * 1024, (u16*)(AsB + 1024));
        gload_lds16(bSrc + k0,             (u16*)(BsB));
        gload_lds16(bSrc + k0 + 16 * 1024, (u16*)(BsB + 1024));
        __syncthreads();
        bf16x8 af[4], bf[4];
#pragma unroll
        for (int mi = 0; mi < 4; mi++)
            af[mi] = *(const bf16x8*)((char*)As + (wm * 64 + mi * 16 + l15) * 64 + l4 * 16);
#pragma unroll
        for (int ni = 0; ni < 4; ni++)
            bf[ni] = *(const bf16x8*)((char*)Bs + (wn * 64 + ni * 16 + l15) * 64 + l4 * 16);
#pragma unroll
        for (int mi = 0; mi < 4; mi++)
#pragma unroll
            for (int ni = 0; ni < 4; ni++)
                acc[mi][ni] = __builtin_amdgcn_mfma_f32_16x16x32_bf16(af[mi], bf[ni], acc[mi][ni], 0, 0, 0);
        __syncthreads();
    }
#pragma unroll
    for (int mi = 0; mi < 4; mi++)
#pragma unroll
        for (int ni = 0; ni < 4; ni++) {
            int col = bn + wn * 64 + ni * 16 + l15;
            int which = col >> 10, f = col & 1023;
            int hh = f >> 6, d = f & 63;
            float bs = bias[col];
#pragma unroll
            for (int r = 0; r < 4; r++) {
                int row = bm + wm * 64 + mi * 16 + l4 * 4 + r;
                int bb = row >> 11, s = row & 2047;
                qkv[(size_t)which * (32 * 2048 * 64) + ((size_t)(bb * 16 + hh) * 2048 + s) * 64 + d] =
                    f2bf(acc[mi][ni][r] + bs);
            }
        }
}

// ---------------------------------------------------------------- Out GEMM 128x128 + residual
__global__ __launch_bounds__(256) void out_gemm128(
    const u16* __restrict__ A, const u16* __restrict__ Bw,
    const float* __restrict__ bias, const float* __restrict__ xres,
    float* __restrict__ out)
{
    __shared__ __align__(16) u16 As[128 * 32];
    __shared__ __align__(16) u16 Bs[128 * 32];
    int t = threadIdx.x;
    int bn = blockIdx.x * 128, bm = blockIdx.y * 128;
    int wid = t >> 6, lane = t & 63;
    int wm = wid >> 1, wn = wid & 1;
    int l15 = lane & 15, l4 = lane >> 4;

    f32x4 zero = {0.f, 0.f, 0.f, 0.f};
    f32x4 acc[4][4];
#pragma unroll
    for (int i = 0; i < 4; i++)
#pragma unroll
        for (int j = 0; j < 4; j++) acc[i][j] = zero;

    const u16* aSrc = A  + (size_t)(bm + wid * 32 + (lane >> 2)) * 1024 + (lane & 3) * 8;
    const u16* bSrc = Bw + (size_t)(bn + wid * 32 + (lane >> 2)) * 1024 + (lane & 3) * 8;
    char* AsB = (char*)As + wid * 2048;
    char* BsB = (char*)Bs + wid * 2048;

    for (int k0 = 0; k0 < 1024; k0 += 32) {
        gload_lds16(aSrc + k0,             (u16*)(AsB));
        gload_lds16(aSrc + k0 + 16 * 1024, (u16*)(AsB + 1024));
        gload_lds16(bSrc + k0,             (u16*)(BsB));
        gload_lds16(bSrc + k0 + 16 * 1024, (u16*)(BsB + 1024));
        __syncthreads();
        bf16x8 af[4], bf[4];
#pragma unroll
        for (int mi = 0; mi < 4; mi++)
            af[mi] = *(const bf16x8*)((char*)As + (wm * 64 + mi * 16 + l15) * 64 + l4 * 16);
#pragma unroll
        for (int ni = 0; ni < 4; ni++)
            bf[ni] = *(const bf16x8*)((char*)Bs + (wn * 64 + ni * 16 + l15) * 64 + l4 * 16);
#pragma unroll
        for (int mi = 0; mi < 4; mi++)
#pragma unroll
            for (int ni = 0; ni < 4; ni++)
                acc[mi][ni] = __builtin_amdgcn_mfma_f32_16x16x32_bf16(af[mi], bf[ni], acc[mi][ni], 0, 0, 0);
        __syncthreads();
    }
#pragma unroll
    for (int mi = 0; mi < 4; mi++)
#pragma unroll
        for (int ni = 0; ni < 4; ni++) {
            int col = bn + wn * 64 + ni * 16 + l15;
            float bs = bias[col];
#pragma unroll
            for (int r = 0; r < 4; r++) {
                int row = bm + wm * 64 + mi * 16 + l4 * 4 + r;
                out[(size_t)row * 1024 + col] = xres[(size_t)row * 1024 + col] + acc[mi][ni][r] + bs;
            }
        }
}

// ---------------------------------------------------------------- Flash attention
// Round-3-proven sync structure. New: conflict-free XOR swizzles on Ks/Vt/P,
// 1024-block grid (one q-tile each) dispatched longest-first, setprio on MFMA.
// Swizzle keys (byte ^= phi(row)<<4 within 128-B rows), verified conflict-free
// under the 8-lane-group b128 model on BOTH write and read sides:
//   Ks: phi = row & 7;  Vt: phi = (d ^ (d>>3)) & 7;  P: phi = q & 7.
__global__ __launch_bounds__(256) void attn_kernel(
    const u16* __restrict__ qbuf, const u16* __restrict__ kbuf,
    const u16* __restrict__ vbuf, u16* __restrict__ ctx)
{
    __shared__ __align__(16) char Ks[64 * 128];
    __shared__ __align__(16) char Vt[64 * 128];
    __shared__ __align__(16) char Pb[4 * 16 * 128];

    int t = threadIdx.x, wid = t >> 6, lane = t & 63;
    int l15 = lane & 15, l4 = lane >> 4;
    int idx = blockIdx.x;
    int qt = 31 - (idx >> 5);          // longest blocks first in dispatch order
    int bh = idx & 31;
    int q0 = qt * 64;
    int sr = t >> 3, g = t & 7, sd8 = g * 8;
    int bb = bh >> 4, hh = bh & 15;
    f32x4 zero = {0.f, 0.f, 0.f, 0.f};

    const u16* Q = qbuf + (size_t)(bh * 2048 + q0 + wid * 16) * 64;
    bf16x8 aq0 = *(const bf16x8*)(Q + l15 * 64 + 8 * l4);
    bf16x8 aq1 = *(const bf16x8*)(Q + l15 * 64 + 32 + 8 * l4);

    f32x4 o[4];
#pragma unroll
    for (int f = 0; f < 4; f++) o[f] = zero;
    float m_run[4] = {-1e30f, -1e30f, -1e30f, -1e30f};
    float l_run[4] = {0.f, 0.f, 0.f, 0.f};

    int kswz = (16 * g) ^ ((sr & 7) << 4);          // staging write col (same for sr, sr+32)
    char* Pw = Pb + wid * 2048;

    for (int kt = 0; kt <= qt; ++kt) {
        int k0 = kt * 64;
        const u16* Kb = kbuf + (size_t)(bh * 2048 + k0) * 64;
        const u16* Vb = vbuf + (size_t)(bh * 2048 + k0) * 64;
        bf16x8 kv0 = *(const bf16x8*)(Kb + sr * 64 + sd8);
        bf16x8 kv1 = *(const bf16x8*)(Kb + (sr + 32) * 64 + sd8);
        bf16x8 vv0 = *(const bf16x8*)(Vb + sr * 64 + sd8);
        bf16x8 vv1 = *(const bf16x8*)(Vb + (sr + 32) * 64 + sd8);
        *(bf16x8*)(Ks + sr * 128 + kswz) = kv0;
        *(bf16x8*)(Ks + (sr + 32) * 128 + kswz) = kv1;
#pragma unroll
        for (int i = 0; i < 8; i++) {
            int d0 = sd8 + i;
            int key = ((d0 ^ (d0 >> 3)) & 7) << 4;
            *(u16*)(Vt + d0 * 128 + ((2 * sr) ^ key)) = (u16)vv0[i];
            *(u16*)(Vt + d0 * 128 + ((2 * sr + 64) ^ key)) = (u16)vv1[i];
        }
        __syncthreads();

        // ---- scores: Q @ K^T
        f32x4 sc[4];
        __builtin_amdgcn_s_setprio(1);
#pragma unroll
        for (int nf = 0; nf < 4; ++nf) {
            int krow = nf * 16 + l15;
            int kkey = (krow & 7) << 4;
            bf16x8 kb0 = *(const bf16x8*)(Ks + krow * 128 + ((16 * l4) ^ kkey));
            bf16x8 kb1 = *(const bf16x8*)(Ks + krow * 128 + ((64 + 16 * l4) ^ kkey));
            f32x4 z = zero;
            z = __builtin_amdgcn_mfma_f32_16x16x32_bf16(aq0, kb0, z, 0, 0, 0);
            z = __builtin_amdgcn_mfma_f32_16x16x32_bf16(aq1, kb1, z, 0, 0, 0);
            sc[nf] = z;
        }
        __builtin_amdgcn_s_setprio(0);

        bool diag = (kt == qt);
#pragma unroll
        for (int nf = 0; nf < 4; nf++)
#pragma unroll
            for (int r = 0; r < 4; r++) {
                float v = sc[nf][r] * 0.125f;
                if (diag) {
                    int qa = wid * 16 + l4 * 4 + r;
                    int ka = nf * 16 + l15;
                    if (ka > qa) v = -1e30f;
                }
                sc[nf][r] = v;
            }
        // ---- online softmax
        float alpha[4];
#pragma unroll
        for (int r = 0; r < 4; r++) {
            float mx = fmaxf(fmaxf(sc[0][r], sc[1][r]), fmaxf(sc[2][r], sc[3][r]));
#pragma unroll
            for (int m = 1; m < 16; m <<= 1) mx = fmaxf(mx, __shfl_xor(mx, m));
            float mn = fmaxf(m_run[r], mx);
            alpha[r] = __expf(m_run[r] - mn);
            float rsum = 0.f;
#pragma unroll
            for (int nf = 0; nf < 4; nf++) {
                float pv = __expf(sc[nf][r] - mn);
                sc[nf][r] = pv; rsum += pv;
            }
#pragma unroll
            for (int m = 1; m < 16; m <<= 1) rsum += __shfl_xor(rsum, m);
            l_run[r] = l_run[r] * alpha[r] + rsum;
            m_run[r] = mn;
        }
#pragma unroll
        for (int f = 0; f < 4; f++)
#pragma unroll
            for (int r = 0; r < 4; r++) o[f][r] *= alpha[r];
        // ---- P -> LDS (wave-private, swizzled)
#pragma unroll
        for (int nf = 0; nf < 4; nf++)
#pragma unroll
            for (int r = 0; r < 4; r++) {
                int q = 4 * l4 + r;
                *(u16*)(Pw + q * 128 + ((32 * nf + 2 * l15) ^ ((q & 7) << 4))) = f2bf(sc[nf][r]);
            }
        // ---- P @ V
        __builtin_amdgcn_s_setprio(1);
#pragma unroll
        for (int kk = 0; kk < 2; kk++) {
            bf16x8 pa = *(const bf16x8*)(Pw + l15 * 128 + ((64 * kk + 16 * l4) ^ ((l15 & 7) << 4)));
#pragma unroll
            for (int f = 0; f < 4; f++) {
                int vrow = f * 16 + l15;
                int vkey = ((vrow ^ (vrow >> 3)) & 7) << 4;
                bf16x8 vb = *(const bf16x8*)(Vt + vrow * 128 + ((64 * kk + 16 * l4) ^ vkey));
                o[f] = __builtin_amdgcn_mfma_f32_16x16x32_bf16(pa, vb, o[f], 0, 0, 0);
            }
        }
        __builtin_amdgcn_s_setprio(0);
        __syncthreads();
    }
    // ---- output
#pragma unroll
    for (int r = 0; r < 4; r++) {
        float inv = 1.f / l_run[r];
        int qa = q0 + wid * 16 + l4 * 4 + r;
        u16* dst = ctx + (size_t)(bb * 2048 + qa) * 1024 + hh * 64;
#pragma unroll
        for (int f = 0; f < 4; f++) dst[f * 16 + l15] = f2bf(o[f][r] * inv);
    }
}

// ----------------------------------------------------------------
extern "C" void kernel_launch(void* const* d_in, const int* in_sizes, int n_in,
                              void* d_out, int out_size, void* d_ws, size_t ws_size,
                              hipStream_t stream)
{
    const float* x    = (const float*)d_in[0];
    const float* ln_g = (const float*)d_in[1];
    const float* ln_b = (const float*)d_in[2];
    const float* wqkv = (const float*)d_in[3];
    const float* bqkv = (const float*)d_in[4];
    const float* wo   = (const float*)d_in[5];
    const float* bo   = (const float*)d_in[6];
    float* out = (float*)d_out;

    char* ws = (char*)d_ws;
    u16* hbuf  = (u16*)ws;                          // 8 MB   (LN out; later woT reuses front)
    u16* qkvb  = (u16*)(ws + 8388608);              // 24 MB  qkv head-major
    u16* ctxb  = (u16*)(ws + 33554432);             // 8 MB   (wqkvT first, then ctx)
    u16* wqkvT = ctxb;                              // 6.29 MB (dead before attn writes ctx)
    u16* woT   = hbuf;                              // 2 MB   (hbuf dead after qkv_gemm)

    transpose_f32_bf16<<<dim3(48, 16), 256, 0, stream>>>(wqkv, wqkvT, 1024, 3072);
    ln_kernel<<<4096, 256, 0, stream>>>(x, ln_g, ln_b, hbuf);
    qkv_gemm128<<<dim3(24, 32), 256, 0, stream>>>(hbuf, wqkvT, bqkv, qkvb);
    transpose_f32_bf16<<<dim3(16, 16), 256, 0, stream>>>(wo, woT, 1024, 1024);
    attn_kernel<<<1024, 256, 0, stream>>>(
        qkvb, qkvb + 32 * 2048 * 64, qkvb + 2 * 32 * 2048 * 64, ctxb);
    out_gemm128<<<dim3(8, 32), 256, 0, stream>>>(ctxb, woT, bo, x, out);
}

// Round 5
// 150.126 us; speedup vs baseline: 2.1977x; 1.0576x over previous
//
#include <hip/hip_runtime.h>
#include <hip/hip_bf16.h>

#define B_   2
#define S_   2048
#define H_   16
#define D_   64
#define DIM_ 1024
#define QKV_SZ (32 * 2048 * 64)

typedef __attribute__((ext_vector_type(8))) short bf16x8;
typedef __attribute__((ext_vector_type(4))) float f32x4;
typedef unsigned short u16;

static __device__ __forceinline__ u16 f2bf(float f) {      // RNE
    union { float f; unsigned u; } v; v.f = f;
    unsigned u = v.u;
    unsigned r = (u + 0x7fffu + ((u >> 16) & 1u)) >> 16;
    return (u16)r;
}
static __device__ __forceinline__ u16 f2bf_fast(float f) { // round-half-up (P values >= 0)
    union { float f; unsigned u; } v; v.f = f;
    return (u16)((v.u + 0x8000u) >> 16);
}
static __device__ __forceinline__ float exp2_fast(float x) {
    float r; asm("v_exp_f32 %0, %1" : "=v"(r) : "v"(x)); return r;
}
static __device__ __forceinline__ void gload_lds16(const u16* g, u16* l) {
    __builtin_amdgcn_global_load_lds(
        (const __attribute__((address_space(1))) void*)g,
        (__attribute__((address_space(3))) void*)l, 16, 0, 0);
}

// ---------------------------------------------------------------- LayerNorm
__global__ __launch_bounds__(256) void ln_kernel(
    const float* __restrict__ x, const float* __restrict__ g,
    const float* __restrict__ b, u16* __restrict__ hb)
{
    int row = blockIdx.x;
    int t = threadIdx.x;
    const float4 v = ((const float4*)(x + row * DIM_))[t];
    float s  = v.x + v.y + v.z + v.w;
    float ss = v.x*v.x + v.y*v.y + v.z*v.z + v.w*v.w;
#pragma unroll
    for (int m = 1; m < 64; m <<= 1) { s += __shfl_xor(s, m); ss += __shfl_xor(ss, m); }
    __shared__ float rs[4], rss[4];
    int wid = t >> 6, lane = t & 63;
    if (lane == 0) { rs[wid] = s; rss[wid] = ss; }
    __syncthreads();
    s  = rs[0] + rs[1] + rs[2] + rs[3];
    ss = rss[0] + rss[1] + rss[2] + rss[3];
    float mu   = s * (1.0f / DIM_);
    float var  = ss * (1.0f / DIM_) - mu * mu;
    float rstd = rsqrtf(var + 1e-6f);
    const float4 gv = ((const float4*)g)[t];
    const float4 bv = ((const float4*)b)[t];
    ushort4 ov;
    ov.x = f2bf((v.x - mu) * rstd * gv.x + bv.x);
    ov.y = f2bf((v.y - mu) * rstd * gv.y + bv.y);
    ov.z = f2bf((v.z - mu) * rstd * gv.z + bv.z);
    ov.w = f2bf((v.w - mu) * rstd * gv.w + bv.w);
    ((ushort4*)(hb + row * DIM_))[t] = ov;
}

// ---------------------------------------------------------------- fp32 -> bf16 transpose
__global__ __launch_bounds__(256) void transpose_f32_bf16(
    const float* __restrict__ src, u16* __restrict__ dst, int R, int C)
{
    __shared__ u16 T[64][65];
    int c0 = blockIdx.x * 64, r0 = blockIdx.y * 64;
    int t = threadIdx.x;
    int rl = t >> 4, cl = (t & 15) * 4;
#pragma unroll
    for (int p = 0; p < 4; p++) {
        float4 v = *(const float4*)(src + (size_t)(r0 + rl + p * 16) * C + c0 + cl);
        T[cl + 0][rl + p * 16] = f2bf(v.x);
        T[cl + 1][rl + p * 16] = f2bf(v.y);
        T[cl + 2][rl + p * 16] = f2bf(v.z);
        T[cl + 3][rl + p * 16] = f2bf(v.w);
    }
    __syncthreads();
#pragma unroll
    for (int p = 0; p < 4; p++) {
        ushort4 o;
        o.x = T[rl + p * 16][cl + 0];
        o.y = T[rl + p * 16][cl + 1];
        o.z = T[rl + p * 16][cl + 2];
        o.w = T[rl + p * 16][cl + 3];
        *(ushort4*)(dst + (size_t)(c0 + rl + p * 16) * R + r0 + cl) = o;
    }
}

// ---------------------------------------------------------------- QKV GEMM 128x128
// Epilogue: Q pre-scaled by 0.125*log2(e) (softmax done in exp2 domain),
// K written [bh][s][64], V written TRANSPOSED [bh][d][s] (8B packed stores).
__global__ __launch_bounds__(256) void qkv_gemm128(
    const u16* __restrict__ A, const u16* __restrict__ Bw,
    const float* __restrict__ bias, u16* __restrict__ qkv)
{
    __shared__ __align__(16) u16 As[128 * 32];
    __shared__ __align__(16) u16 Bs[128 * 32];
    int t = threadIdx.x;
    int bn = blockIdx.x * 128, bm = blockIdx.y * 128;
    int wid = t >> 6, lane = t & 63;
    int wm = wid >> 1, wn = wid & 1;
    int l15 = lane & 15, l4 = lane >> 4;

    f32x4 zero = {0.f, 0.f, 0.f, 0.f};
    f32x4 acc[4][4];
#pragma unroll
    for (int i = 0; i < 4; i++)
#pragma unroll
        for (int j = 0; j < 4; j++) acc[i][j] = zero;

    const u16* aSrc = A  + (size_t)(bm + wid * 32 + (lane >> 2)) * 1024 + (lane & 3) * 8;
    const u16* bSrc = Bw + (size_t)(bn + wid * 32 + (lane >> 2)) * 1024 + (lane & 3) * 8;
    char* AsB = (char*)As + wid * 2048;
    char* BsB = (char*)Bs + wid * 2048;

    for (int k0 = 0; k0 < 1024; k0 += 32) {
        gload_lds16(aSrc + k0,             (u16*)(AsB));
        gload_lds16(aSrc + k0 + 16 * 1024, (u16*)(AsB + 1024));
        gload_lds16(bSrc + k0,             (u16*)(BsB));
        gload_lds16(bSrc + k0 + 16 * 1024, (u16*)(BsB + 1024));
        __syncthreads();
        bf16x8 af[4], bf[4];
#pragma unroll
        for (int mi = 0; mi < 4; mi++)
            af[mi] = *(const bf16x8*)((char*)As + (wm * 64 + mi * 16 + l15) * 64 + l4 * 16);
#pragma unroll
        for (int ni = 0; ni < 4; ni++)
            bf[ni] = *(const bf16x8*)((char*)Bs + (wn * 64 + ni * 16 + l15) * 64 + l4 * 16);
#pragma unroll
        for (int mi = 0; mi < 4; mi++)
#pragma unroll
            for (int ni = 0; ni < 4; ni++)
                acc[mi][ni] = __builtin_amdgcn_mfma_f32_16x16x32_bf16(af[mi], bf[ni], acc[mi][ni], 0, 0, 0);
        __syncthreads();
    }
#pragma unroll
    for (int mi = 0; mi < 4; mi++)
#pragma unroll
        for (int ni = 0; ni < 4; ni++) {
            int col = bn + wn * 64 + ni * 16 + l15;
            int which = col >> 10, f = col & 1023;
            int hh = f >> 6, d = f & 63;
            float bs = bias[col];
            if (which == 2) {
                // V^T [32][64][2048]; 4 consecutive s per lane -> one 8B store
                int s_base = bm + wm * 64 + mi * 16 + l4 * 4;
                int bb = s_base >> 11, s = s_base & 2047;
                ushort4 pk;
                pk.x = f2bf(acc[mi][ni][0] + bs);
                pk.y = f2bf(acc[mi][ni][1] + bs);
                pk.z = f2bf(acc[mi][ni][2] + bs);
                pk.w = f2bf(acc[mi][ni][3] + bs);
                *(ushort4*)(qkv + (size_t)2 * QKV_SZ +
                            ((size_t)(bb * 16 + hh) * 64 + d) * 2048 + s) = pk;
            } else {
                float scl = (which == 0) ? 0.18033688011112042f : 1.0f; // 0.125*log2(e)
#pragma unroll
                for (int r = 0; r < 4; r++) {
                    int row = bm + wm * 64 + mi * 16 + l4 * 4 + r;
                    int bb = row >> 11, s = row & 2047;
                    qkv[(size_t)which * QKV_SZ + ((size_t)(bb * 16 + hh) * 2048 + s) * 64 + d] =
                        f2bf((acc[mi][ni][r] + bs) * scl);
                }
            }
        }
}

// ---------------------------------------------------------------- Out GEMM 128x128 + residual
__global__ __launch_bounds__(256) void out_gemm128(
    const u16* __restrict__ A, const u16* __restrict__ Bw,
    const float* __restrict__ bias, const float* __restrict__ xres,
    float* __restrict__ out)
{
    __shared__ __align__(16) u16 As[128 * 32];
    __shared__ __align__(16) u16 Bs[128 * 32];
    int t = threadIdx.x;
    int bn = blockIdx.x * 128, bm = blockIdx.y * 128;
    int wid = t >> 6, lane = t & 63;
    int wm = wid >> 1, wn = wid & 1;
    int l15 = lane & 15, l4 = lane >> 4;

    f32x4 zero = {0.f, 0.f, 0.f, 0.f};
    f32x4 acc[4][4];
#pragma unroll
    for (int i = 0; i < 4; i++)
#pragma unroll
        for (int j = 0; j < 4; j++) acc[i][j] = zero;

    const u16* aSrc = A  + (size_t)(bm + wid * 32 + (lane >> 2)) * 1024 + (lane & 3) * 8;
    const u16* bSrc = Bw + (size_t)(bn + wid * 32 + (lane >> 2)) * 1024 + (lane & 3) * 8;
    char* AsB = (char*)As + wid * 2048;
    char* BsB = (char*)Bs + wid * 2048;

    for (int k0 = 0; k0 < 1024; k0 += 32) {
        gload_lds16(aSrc + k0,             (u16*)(AsB));
        gload_lds16(aSrc + k0 + 16 * 1024, (u16*)(AsB + 1024));
        gload_lds16(bSrc + k0,             (u16*)(BsB));
        gload_lds16(bSrc + k0 + 16 * 1024, (u16*)(BsB + 1024));
        __syncthreads();
        bf16x8 af[4], bf[4];
#pragma unroll
        for (int mi = 0; mi < 4; mi++)
            af[mi] = *(const bf16x8*)((char*)As + (wm * 64 + mi * 16 + l15) * 64 + l4 * 16);
#pragma unroll
        for (int ni = 0; ni < 4; ni++)
            bf[ni] = *(const bf16x8*)((char*)Bs + (wn * 64 + ni * 16 + l15) * 64 + l4 * 16);
#pragma unroll
        for (int mi = 0; mi < 4; mi++)
#pragma unroll
            for (int ni = 0; ni < 4; ni++)
                acc[mi][ni] = __builtin_amdgcn_mfma_f32_16x16x32_bf16(af[mi], bf[ni], acc[mi][ni], 0, 0, 0);
        __syncthreads();
    }
#pragma unroll
    for (int mi = 0; mi < 4; mi++)
#pragma unroll
        for (int ni = 0; ni < 4; ni++) {
            int col = bn + wn * 64 + ni * 16 + l15;
            float bs = bias[col];
#pragma unroll
            for (int r = 0; r < 4; r++) {
                int row = bm + wm * 64 + mi * 16 + l4 * 4 + r;
                out[(size_t)row * 1024 + col] = xres[(size_t)row * 1024 + col] + acc[mi][ni][r] + bs;
            }
        }
}

// ---------------------------------------------------------------- Flash attention
// K: [bh][s][64]; V: TRANSPOSED [bh][d][s] (both staged identically, b128 only).
// Q pre-scaled by 0.125*log2(e); softmax in exp2 domain via raw v_exp_f32.
// Defer-max (THR=10, wave-uniform). Clamped register prefetch of tile kt+1.
// Swizzles (byte ^= phi<<4, 128B rows): Ks/Vt phi=row&7; P phi=(q^(q>>2))&7.
__global__ __launch_bounds__(256) void attn_kernel(
    const u16* __restrict__ qbuf, const u16* __restrict__ kbuf,
    const u16* __restrict__ vbuf, u16* __restrict__ ctx)
{
    __shared__ __align__(16) char Ks[64 * 128];
    __shared__ __align__(16) char Vt[64 * 128];
    __shared__ __align__(16) char Pb[4 * 16 * 128];

    int t = threadIdx.x, wid = t >> 6, lane = t & 63;
    int l15 = lane & 15, l4 = lane >> 4;
    int idx = blockIdx.x;
    int qt = 31 - (idx >> 5);          // longest blocks first
    int bh = idx & 31;
    int q0 = qt * 64;
    int sr = t >> 3, g = t & 7;
    int bb = bh >> 4, hh = bh & 15;
    f32x4 zero = {0.f, 0.f, 0.f, 0.f};

    const u16* Q = qbuf + (size_t)(bh * 2048 + q0 + wid * 16) * 64;
    bf16x8 aq0 = *(const bf16x8*)(Q + l15 * 64 + 8 * l4);
    bf16x8 aq1 = *(const bf16x8*)(Q + l15 * 64 + 32 + 8 * l4);

    f32x4 o[4];
#pragma unroll
    for (int f = 0; f < 4; f++) o[f] = zero;
    float m_run[4] = {-1e30f, -1e30f, -1e30f, -1e30f};
    float l_run[4] = {0.f, 0.f, 0.f, 0.f};

    int kswz = (16 * g) ^ ((sr & 7) << 4);
    char* Pw = Pb + wid * 2048;
    int pkey = ((l15 ^ (l15 >> 2)) & 7) << 4;

    const u16* Kbase = kbuf + (size_t)bh * 2048 * 64;      // [s][64]
    const u16* Vbase = vbuf + (size_t)bh * 64 * 2048;      // [d][s]

    // preload tile 0
    bf16x8 ck0 = *(const bf16x8*)(Kbase + (size_t)sr * 64 + g * 8);
    bf16x8 ck1 = *(const bf16x8*)(Kbase + (size_t)(sr + 32) * 64 + g * 8);
    bf16x8 cv0 = *(const bf16x8*)(Vbase + (size_t)sr * 2048 + g * 8);
    bf16x8 cv1 = *(const bf16x8*)(Vbase + (size_t)(sr + 32) * 2048 + g * 8);

    for (int kt = 0; kt <= qt; ++kt) {
        // ---- write current tile to LDS (swizzled, b128 only)
        *(bf16x8*)(Ks + sr * 128 + kswz) = ck0;
        *(bf16x8*)(Ks + (sr + 32) * 128 + kswz) = ck1;
        *(bf16x8*)(Vt + sr * 128 + kswz) = cv0;
        *(bf16x8*)(Vt + (sr + 32) * 128 + kswz) = cv1;
        // ---- prefetch next tile (clamped -> always initialized, deterministic)
        {
            int nkt = (kt < qt) ? kt + 1 : qt;
            const u16* Kn = Kbase + (size_t)nkt * 64 * 64;
            const u16* Vn = Vbase + (size_t)nkt * 64;
            bf16x8 a = *(const bf16x8*)(Kn + (size_t)sr * 64 + g * 8);
            bf16x8 b = *(const bf16x8*)(Kn + (size_t)(sr + 32) * 64 + g * 8);
            bf16x8 c = *(const bf16x8*)(Vn + (size_t)sr * 2048 + g * 8);
            bf16x8 d = *(const bf16x8*)(Vn + (size_t)(sr + 32) * 2048 + g * 8);
            __syncthreads();

            // ---- scores: Q @ K^T (exp2-domain, Q pre-scaled)
            f32x4 sc[4];
            __builtin_amdgcn_s_setprio(1);
#pragma unroll
            for (int nf = 0; nf < 4; ++nf) {
                int krow = nf * 16 + l15;
                int kkey = (krow & 7) << 4;
                bf16x8 kb0 = *(const bf16x8*)(Ks + krow * 128 + ((16 * l4) ^ kkey));
                bf16x8 kb1 = *(const bf16x8*)(Ks + krow * 128 + ((64 + 16 * l4) ^ kkey));
                f32x4 z = zero;
                z = __builtin_amdgcn_mfma_f32_16x16x32_bf16(aq0, kb0, z, 0, 0, 0);
                z = __builtin_amdgcn_mfma_f32_16x16x32_bf16(aq1, kb1, z, 0, 0, 0);
                sc[nf] = z;
            }
            __builtin_amdgcn_s_setprio(0);

            if (kt == qt) {
#pragma unroll
                for (int nf = 0; nf < 4; nf++)
#pragma unroll
                    for (int r = 0; r < 4; r++) {
                        int qa = wid * 16 + l4 * 4 + r;
                        int ka = nf * 16 + l15;
                        if (ka > qa) sc[nf][r] = -1e30f;
                    }
            }
            // ---- online softmax (exp2 domain)
            float mx[4];
#pragma unroll
            for (int r = 0; r < 4; r++) {
                float m0 = fmaxf(fmaxf(sc[0][r], sc[1][r]), fmaxf(sc[2][r], sc[3][r]));
#pragma unroll
                for (int m = 1; m < 16; m <<= 1) m0 = fmaxf(m0, __shfl_xor(m0, m));
                mx[r] = m0;
            }
            bool need = (mx[0] > m_run[0] + 10.f) | (mx[1] > m_run[1] + 10.f) |
                        (mx[2] > m_run[2] + 10.f) | (mx[3] > m_run[3] + 10.f);
            if (__any(need)) {
#pragma unroll
                for (int r = 0; r < 4; r++) {
                    float mn = fmaxf(m_run[r], mx[r]);
                    float al = exp2_fast(m_run[r] - mn);
                    l_run[r] *= al;
                    m_run[r] = mn;
#pragma unroll
                    for (int f = 0; f < 4; f++) o[f][r] *= al;
                }
            }
#pragma unroll
            for (int r = 0; r < 4; r++) {
                float rsum = 0.f;
#pragma unroll
                for (int nf = 0; nf < 4; nf++) {
                    float pv = exp2_fast(sc[nf][r] - m_run[r]);
                    sc[nf][r] = pv; rsum += pv;
                }
#pragma unroll
                for (int m = 1; m < 16; m <<= 1) rsum += __shfl_xor(rsum, m);
                l_run[r] += rsum;
            }
            // ---- P -> LDS (wave-private, swizzled)
#pragma unroll
            for (int r = 0; r < 4; r++) {
                int q = 4 * l4 + r;
                int key = ((q ^ (q >> 2)) & 7) << 4;
#pragma unroll
                for (int nf = 0; nf < 4; nf++)
                    *(u16*)(Pw + q * 128 + ((32 * nf + 2 * l15) ^ key)) = f2bf_fast(sc[nf][r]);
            }
            // ---- P @ V
            __builtin_amdgcn_s_setprio(1);
#pragma unroll
            for (int kk = 0; kk < 2; kk++) {
                bf16x8 pa = *(const bf16x8*)(Pw + l15 * 128 + ((64 * kk + 16 * l4) ^ pkey));
#pragma unroll
                for (int f = 0; f < 4; f++) {
                    int vrow = f * 16 + l15;
                    int vkey = (vrow & 7) << 4;
                    bf16x8 vb = *(const bf16x8*)(Vt + vrow * 128 + ((64 * kk + 16 * l4) ^ vkey));
                    o[f] = __builtin_amdgcn_mfma_f32_16x16x32_bf16(pa, vb, o[f], 0, 0, 0);
                }
            }
            __builtin_amdgcn_s_setprio(0);
            __syncthreads();
            ck0 = a; ck1 = b; cv0 = c; cv1 = d;
        }
    }
    // ---- output
#pragma unroll
    for (int r = 0; r < 4; r++) {
        float inv = 1.f / l_run[r];
        int qa = q0 + wid * 16 + l4 * 4 + r;
        u16* dst = ctx + (size_t)(bb * 2048 + qa) * 1024 + hh * 64;
#pragma unroll
        for (int f = 0; f < 4; f++) dst[f * 16 + l15] = f2bf(o[f][r] * inv);
    }
}

// ----------------------------------------------------------------
extern "C" void kernel_launch(void* const* d_in, const int* in_sizes, int n_in,
                              void* d_out, int out_size, void* d_ws, size_t ws_size,
                              hipStream_t stream)
{
    const float* x    = (const float*)d_in[0];
    const float* ln_g = (const float*)d_in[1];
    const float* ln_b = (const float*)d_in[2];
    const float* wqkv = (const float*)d_in[3];
    const float* bqkv = (const float*)d_in[4];
    const float* wo   = (const float*)d_in[5];
    const float* bo   = (const float*)d_in[6];
    float* out = (float*)d_out;

    char* ws = (char*)d_ws;
    u16* hbuf  = (u16*)ws;                          // 8 MB   (LN out; later woT reuses front)
    u16* qkvb  = (u16*)(ws + 8388608);              // 24 MB  q/k head-major, v transposed
    u16* ctxb  = (u16*)(ws + 33554432);             // 8 MB   (wqkvT first, then ctx)
    u16* wqkvT = ctxb;                              // 6.29 MB (dead before attn writes ctx)
    u16* woT   = hbuf;                              // 2 MB   (hbuf dead after qkv_gemm)

    transpose_f32_bf16<<<dim3(48, 16), 256, 0, stream>>>(wqkv, wqkvT, 1024, 3072);
    ln_kernel<<<4096, 256, 0, stream>>>(x, ln_g, ln_b, hbuf);
    qkv_gemm128<<<dim3(24, 32), 256, 0, stream>>>(hbuf, wqkvT, bqkv, qkvb);
    transpose_f32_bf16<<<dim3(16, 16), 256, 0, stream>>>(wo, woT, 1024, 1024);
    attn_kernel<<<1024, 256, 0, stream>>>(
        qkvb, qkvb + QKV_SZ, qkvb + 2 * QKV_SZ, ctxb);
    out_gemm128<<<dim3(8, 32), 256, 0, stream>>>(ctxb, woT, bo, x, out);
}

// Round 6
// 129.115 us; speedup vs baseline: 2.5553x; 1.1627x over previous
//
#include <hip/hip_runtime.h>
#include <hip/hip_bf16.h>

#define B_   2
#define S_   2048
#define H_   16
#define D_   64
#define DIM_ 1024
#define QKV_SZ (32 * 2048 * 64)

typedef __attribute__((ext_vector_type(8))) short bf16x8;
typedef __attribute__((ext_vector_type(4))) float f32x4;
typedef unsigned short u16;
typedef unsigned int u32;

static __device__ __forceinline__ u16 f2bf(float f) {      // RNE
    union { float f; unsigned u; } v; v.f = f;
    unsigned u = v.u;
    unsigned r = (u + 0x7fffu + ((u >> 16) & 1u)) >> 16;
    return (u16)r;
}
static __device__ __forceinline__ float exp2_fast(float x) {
    float r; asm("v_exp_f32 %0, %1" : "=v"(r) : "v"(x)); return r;
}
static __device__ __forceinline__ u32 cvtpk_bf16(float lo, float hi) {
    u32 r; asm("v_cvt_pk_bf16_f32 %0, %1, %2" : "=v"(r) : "v"(lo), "v"(hi)); return r;
}
static __device__ __forceinline__ void gload_lds16(const u16* g, u16* l) {
    __builtin_amdgcn_global_load_lds(
        (const __attribute__((address_space(1))) void*)g,
        (__attribute__((address_space(3))) void*)l, 16, 0, 0);
}

// ---------------------------------------------------------------- LayerNorm
__global__ __launch_bounds__(256) void ln_kernel(
    const float* __restrict__ x, const float* __restrict__ g,
    const float* __restrict__ b, u16* __restrict__ hb)
{
    int row = blockIdx.x;
    int t = threadIdx.x;
    const float4 v = ((const float4*)(x + row * DIM_))[t];
    float s  = v.x + v.y + v.z + v.w;
    float ss = v.x*v.x + v.y*v.y + v.z*v.z + v.w*v.w;
#pragma unroll
    for (int m = 1; m < 64; m <<= 1) { s += __shfl_xor(s, m); ss += __shfl_xor(ss, m); }
    __shared__ float rs[4], rss[4];
    int wid = t >> 6, lane = t & 63;
    if (lane == 0) { rs[wid] = s; rss[wid] = ss; }
    __syncthreads();
    s  = rs[0] + rs[1] + rs[2] + rs[3];
    ss = rss[0] + rss[1] + rss[2] + rss[3];
    float mu   = s * (1.0f / DIM_);
    float var  = ss * (1.0f / DIM_) - mu * mu;
    float rstd = rsqrtf(var + 1e-6f);
    const float4 gv = ((const float4*)g)[t];
    const float4 bv = ((const float4*)b)[t];
    ushort4 ov;
    ov.x = f2bf((v.x - mu) * rstd * gv.x + bv.x);
    ov.y = f2bf((v.y - mu) * rstd * gv.y + bv.y);
    ov.z = f2bf((v.z - mu) * rstd * gv.z + bv.z);
    ov.w = f2bf((v.w - mu) * rstd * gv.w + bv.w);
    ((ushort4*)(hb + row * DIM_))[t] = ov;
}

// ---------------------------------------------------------------- fp32 -> bf16 transpose
__global__ __launch_bounds__(256) void transpose_f32_bf16(
    const float* __restrict__ src, u16* __restrict__ dst, int R, int C)
{
    __shared__ u16 T[64][65];
    int c0 = blockIdx.x * 64, r0 = blockIdx.y * 64;
    int t = threadIdx.x;
    int rl = t >> 4, cl = (t & 15) * 4;
#pragma unroll
    for (int p = 0; p < 4; p++) {
        float4 v = *(const float4*)(src + (size_t)(r0 + rl + p * 16) * C + c0 + cl);
        T[cl + 0][rl + p * 16] = f2bf(v.x);
        T[cl + 1][rl + p * 16] = f2bf(v.y);
        T[cl + 2][rl + p * 16] = f2bf(v.z);
        T[cl + 3][rl + p * 16] = f2bf(v.w);
    }
    __syncthreads();
#pragma unroll
    for (int p = 0; p < 4; p++) {
        ushort4 o;
        o.x = T[rl + p * 16][cl + 0];
        o.y = T[rl + p * 16][cl + 1];
        o.z = T[rl + p * 16][cl + 2];
        o.w = T[rl + p * 16][cl + 3];
        *(ushort4*)(dst + (size_t)(c0 + rl + p * 16) * R + r0 + cl) = o;
    }
}

// ---------------------------------------------------------------- QKV GEMM 128x128
// Epilogue: Q pre-scaled by 0.125*log2(e) (softmax in exp2 domain),
// K written [bh][s][64], V written TRANSPOSED [bh][d][s].
__global__ __launch_bounds__(256) void qkv_gemm128(
    const u16* __restrict__ A, const u16* __restrict__ Bw,
    const float* __restrict__ bias, u16* __restrict__ qkv)
{
    __shared__ __align__(16) u16 As[128 * 32];
    __shared__ __align__(16) u16 Bs[128 * 32];
    int t = threadIdx.x;
    int bn = blockIdx.x * 128, bm = blockIdx.y * 128;
    int wid = t >> 6, lane = t & 63;
    int wm = wid >> 1, wn = wid & 1;
    int l15 = lane & 15, l4 = lane >> 4;

    f32x4 zero = {0.f, 0.f, 0.f, 0.f};
    f32x4 acc[4][4];
#pragma unroll
    for (int i = 0; i < 4; i++)
#pragma unroll
        for (int j = 0; j < 4; j++) acc[i][j] = zero;

    const u16* aSrc = A  + (size_t)(bm + wid * 32 + (lane >> 2)) * 1024 + (lane & 3) * 8;
    const u16* bSrc = Bw + (size_t)(bn + wid * 32 + (lane >> 2)) * 1024 + (lane & 3) * 8;
    char* AsB = (char*)As + wid * 2048;
    char* BsB = (char*)Bs + wid * 2048;

    for (int k0 = 0; k0 < 1024; k0 += 32) {
        gload_lds16(aSrc + k0,             (u16*)(AsB));
        gload_lds16(aSrc + k0 + 16 * 1024, (u16*)(AsB + 1024));
        gload_lds16(bSrc + k0,             (u16*)(BsB));
        gload_lds16(bSrc + k0 + 16 * 1024, (u16*)(BsB + 1024));
        __syncthreads();
        bf16x8 af[4], bf[4];
#pragma unroll
        for (int mi = 0; mi < 4; mi++)
            af[mi] = *(const bf16x8*)((char*)As + (wm * 64 + mi * 16 + l15) * 64 + l4 * 16);
#pragma unroll
        for (int ni = 0; ni < 4; ni++)
            bf[ni] = *(const bf16x8*)((char*)Bs + (wn * 64 + ni * 16 + l15) * 64 + l4 * 16);
#pragma unroll
        for (int mi = 0; mi < 4; mi++)
#pragma unroll
            for (int ni = 0; ni < 4; ni++)
                acc[mi][ni] = __builtin_amdgcn_mfma_f32_16x16x32_bf16(af[mi], bf[ni], acc[mi][ni], 0, 0, 0);
        __syncthreads();
    }
#pragma unroll
    for (int mi = 0; mi < 4; mi++)
#pragma unroll
        for (int ni = 0; ni < 4; ni++) {
            int col = bn + wn * 64 + ni * 16 + l15;
            int which = col >> 10, f = col & 1023;
            int hh = f >> 6, d = f & 63;
            float bs = bias[col];
            if (which == 2) {
                int s_base = bm + wm * 64 + mi * 16 + l4 * 4;
                int bb = s_base >> 11, s = s_base & 2047;
                ushort4 pk;
                pk.x = f2bf(acc[mi][ni][0] + bs);
                pk.y = f2bf(acc[mi][ni][1] + bs);
                pk.z = f2bf(acc[mi][ni][2] + bs);
                pk.w = f2bf(acc[mi][ni][3] + bs);
                *(ushort4*)(qkv + (size_t)2 * QKV_SZ +
                            ((size_t)(bb * 16 + hh) * 64 + d) * 2048 + s) = pk;
            } else {
                float scl = (which == 0) ? 0.18033688011112042f : 1.0f; // 0.125*log2(e)
#pragma unroll
                for (int r = 0; r < 4; r++) {
                    int row = bm + wm * 64 + mi * 16 + l4 * 4 + r;
                    int bb = row >> 11, s = row & 2047;
                    qkv[(size_t)which * QKV_SZ + ((size_t)(bb * 16 + hh) * 2048 + s) * 64 + d] =
                        f2bf((acc[mi][ni][r] + bs) * scl);
                }
            }
        }
}

// ---------------------------------------------------------------- Out GEMM 128x128 + residual
__global__ __launch_bounds__(256) void out_gemm128(
    const u16* __restrict__ A, const u16* __restrict__ Bw,
    const float* __restrict__ bias, const float* __restrict__ xres,
    float* __restrict__ out)
{
    __shared__ __align__(16) u16 As[128 * 32];
    __shared__ __align__(16) u16 Bs[128 * 32];
    int t = threadIdx.x;
    int bn = blockIdx.x * 128, bm = blockIdx.y * 128;
    int wid = t >> 6, lane = t & 63;
    int wm = wid >> 1, wn = wid & 1;
    int l15 = lane & 15, l4 = lane >> 4;

    f32x4 zero = {0.f, 0.f, 0.f, 0.f};
    f32x4 acc[4][4];
#pragma unroll
    for (int i = 0; i < 4; i++)
#pragma unroll
        for (int j = 0; j < 4; j++) acc[i][j] = zero;

    const u16* aSrc = A  + (size_t)(bm + wid * 32 + (lane >> 2)) * 1024 + (lane & 3) * 8;
    const u16* bSrc = Bw + (size_t)(bn + wid * 32 + (lane >> 2)) * 1024 + (lane & 3) * 8;
    char* AsB = (char*)As + wid * 2048;
    char* BsB = (char*)Bs + wid * 2048;

    for (int k0 = 0; k0 < 1024; k0 += 32) {
        gload_lds16(aSrc + k0,             (u16*)(AsB));
        gload_lds16(aSrc + k0 + 16 * 1024, (u16*)(AsB + 1024));
        gload_lds16(bSrc + k0,             (u16*)(BsB));
        gload_lds16(bSrc + k0 + 16 * 1024, (u16*)(BsB + 1024));
        __syncthreads();
        bf16x8 af[4], bf[4];
#pragma unroll
        for (int mi = 0; mi < 4; mi++)
            af[mi] = *(const bf16x8*)((char*)As + (wm * 64 + mi * 16 + l15) * 64 + l4 * 16);
#pragma unroll
        for (int ni = 0; ni < 4; ni++)
            bf[ni] = *(const bf16x8*)((char*)Bs + (wn * 64 + ni * 16 + l15) * 64 + l4 * 16);
#pragma unroll
        for (int mi = 0; mi < 4; mi++)
#pragma unroll
            for (int ni = 0; ni < 4; ni++)
                acc[mi][ni] = __builtin_amdgcn_mfma_f32_16x16x32_bf16(af[mi], bf[ni], acc[mi][ni], 0, 0, 0);
        __syncthreads();
    }
#pragma unroll
    for (int mi = 0; mi < 4; mi++)
#pragma unroll
        for (int ni = 0; ni < 4; ni++) {
            int col = bn + wn * 64 + ni * 16 + l15;
            float bs = bias[col];
#pragma unroll
            for (int r = 0; r < 4; r++) {
                int row = bm + wm * 64 + mi * 16 + l4 * 4 + r;
                out[(size_t)row * 1024 + col] = xres[(size_t)row * 1024 + col] + acc[mi][ni][r] + bs;
            }
        }
}

// ---------------------------------------------------------------- Flash attention
// SWAPPED QK^T: sc = mfma(K, Q) so lane holds sc[nf][r] = S[ka=nf*16+4*l4+r][q=l15].
//  - row sum: per-lane partial, cross-lane reduce ONCE at the end
//  - row max: per-lane local max + __any ballot (defer THR=10); full reduce only on trigger
//  - P write: 4x ds_write_b64 of cvt_pk pairs (k-consecutive per lane)
// K: [bh][s][64]; V: transposed [bh][d][s]. Q pre-scaled by 0.125*log2(e).
// Swizzles (byte ^= (row&7)<<4, 128B rows) on Ks/Vt/P, conflict-free both sides.
__global__ __launch_bounds__(256) void attn_kernel(
    const u16* __restrict__ qbuf, const u16* __restrict__ kbuf,
    const u16* __restrict__ vbuf, u16* __restrict__ ctx)
{
    __shared__ __align__(16) char Ks[64 * 128];
    __shared__ __align__(16) char Vt[64 * 128];
    __shared__ __align__(16) char Pb[4 * 16 * 128];

    int t = threadIdx.x, wid = t >> 6, lane = t & 63;
    int l15 = lane & 15, l4 = lane >> 4;
    int idx = blockIdx.x;
    int qt = 31 - (idx >> 5);          // longest blocks first
    int bh = idx & 31;
    int q0 = qt * 64;
    int sr = t >> 3, g = t & 7;
    int bb = bh >> 4, hh = bh & 15;
    f32x4 zero = {0.f, 0.f, 0.f, 0.f};

    const u16* Q = qbuf + (size_t)(bh * 2048 + q0 + wid * 16) * 64;
    bf16x8 aq0 = *(const bf16x8*)(Q + l15 * 64 + 8 * l4);
    bf16x8 aq1 = *(const bf16x8*)(Q + l15 * 64 + 32 + 8 * l4);

    f32x4 o[4];
#pragma unroll
    for (int f = 0; f < 4; f++) o[f] = zero;
    float m_run = -1e30f;              // running max for q-row (wid*16 + l15)
    float l_run = 0.f;                 // per-lane PARTIAL sum for that row

    int kswz = (16 * g) ^ ((sr & 7) << 4);
    char* Pw = Pb + wid * 2048;
    int prow = l15 * 128;
    int pkey = (l15 & 7) << 4;
    int qloc = wid * 16 + l15;

    const u16* Kbase = kbuf + (size_t)bh * 2048 * 64;      // [s][64]
    const u16* Vbase = vbuf + (size_t)bh * 64 * 2048;      // [d][s]

    bf16x8 ck0 = *(const bf16x8*)(Kbase + (size_t)sr * 64 + g * 8);
    bf16x8 ck1 = *(const bf16x8*)(Kbase + (size_t)(sr + 32) * 64 + g * 8);
    bf16x8 cv0 = *(const bf16x8*)(Vbase + (size_t)sr * 2048 + g * 8);
    bf16x8 cv1 = *(const bf16x8*)(Vbase + (size_t)(sr + 32) * 2048 + g * 8);

    for (int kt = 0; kt <= qt; ++kt) {
        *(bf16x8*)(Ks + sr * 128 + kswz) = ck0;
        *(bf16x8*)(Ks + (sr + 32) * 128 + kswz) = ck1;
        *(bf16x8*)(Vt + sr * 128 + kswz) = cv0;
        *(bf16x8*)(Vt + (sr + 32) * 128 + kswz) = cv1;
        {
            int nkt = (kt < qt) ? kt + 1 : qt;   // clamped -> always initialized
            const u16* Kn = Kbase + (size_t)nkt * 64 * 64;
            const u16* Vn = Vbase + (size_t)nkt * 64;
            bf16x8 a = *(const bf16x8*)(Kn + (size_t)sr * 64 + g * 8);
            bf16x8 b = *(const bf16x8*)(Kn + (size_t)(sr + 32) * 64 + g * 8);
            bf16x8 c = *(const bf16x8*)(Vn + (size_t)sr * 2048 + g * 8);
            bf16x8 d = *(const bf16x8*)(Vn + (size_t)(sr + 32) * 2048 + g * 8);
            __syncthreads();

            // ---- scores (swapped): sc[nf][r] = S[ka=nf*16+4*l4+r][q=l15]
            f32x4 sc[4];
            __builtin_amdgcn_s_setprio(1);
#pragma unroll
            for (int nf = 0; nf < 4; ++nf) {
                int krow = nf * 16 + l15;
                int kkey = (krow & 7) << 4;
                bf16x8 kb0 = *(const bf16x8*)(Ks + krow * 128 + ((16 * l4) ^ kkey));
                bf16x8 kb1 = *(const bf16x8*)(Ks + krow * 128 + ((64 + 16 * l4) ^ kkey));
                f32x4 z = zero;
                z = __builtin_amdgcn_mfma_f32_16x16x32_bf16(kb0, aq0, z, 0, 0, 0);
                z = __builtin_amdgcn_mfma_f32_16x16x32_bf16(kb1, aq1, z, 0, 0, 0);
                sc[nf] = z;
            }
            __builtin_amdgcn_s_setprio(0);

            if (kt == qt) {
#pragma unroll
                for (int nf = 0; nf < 4; nf++)
#pragma unroll
                    for (int r = 0; r < 4; r++) {
                        int ka = nf * 16 + 4 * l4 + r;
                        if (ka > qloc) sc[nf][r] = -1e30f;
                    }
            }
            // ---- local max + deferred global max
            float lmax = sc[0][0];
#pragma unroll
            for (int nf = 0; nf < 4; nf++)
#pragma unroll
                for (int r = 0; r < 4; r++) lmax = fmaxf(lmax, sc[nf][r]);
            if (__any(lmax > m_run + 10.f)) {
                float m0 = lmax;
                m0 = fmaxf(m0, __shfl_xor(m0, 16));
                m0 = fmaxf(m0, __shfl_xor(m0, 32));
                float mn = fmaxf(m_run, m0);
                float al = exp2_fast(m_run - mn);
                l_run *= al;
                m_run = mn;
                float a0 = __shfl(al, 4 * l4 + 0);
                float a1 = __shfl(al, 4 * l4 + 1);
                float a2 = __shfl(al, 4 * l4 + 2);
                float a3 = __shfl(al, 4 * l4 + 3);
#pragma unroll
                for (int f = 0; f < 4; f++) {
                    o[f][0] *= a0; o[f][1] *= a1; o[f][2] *= a2; o[f][3] *= a3;
                }
            }
            // ---- exp2 + per-lane partial sum
            float psum = 0.f;
#pragma unroll
            for (int nf = 0; nf < 4; nf++)
#pragma unroll
                for (int r = 0; r < 4; r++) {
                    float pv = exp2_fast(sc[nf][r] - m_run);
                    sc[nf][r] = pv; psum += pv;
                }
            l_run += psum;
            // ---- P pack + write (k-consecutive quad per lane)
#pragma unroll
            for (int nf = 0; nf < 4; nf++) {
                uint2 w;
                w.x = cvtpk_bf16(sc[nf][0], sc[nf][1]);
                w.y = cvtpk_bf16(sc[nf][2], sc[nf][3]);
                *(uint2*)(Pw + prow + ((nf * 32 + l4 * 8) ^ pkey)) = w;
            }
            // ---- P @ V
            __builtin_amdgcn_s_setprio(1);
#pragma unroll
            for (int kk = 0; kk < 2; kk++) {
                bf16x8 pa = *(const bf16x8*)(Pw + prow + ((64 * kk + 16 * l4) ^ pkey));
#pragma unroll
                for (int f = 0; f < 4; f++) {
                    int vrow = f * 16 + l15;
                    int vkey = (vrow & 7) << 4;
                    bf16x8 vb = *(const bf16x8*)(Vt + vrow * 128 + ((64 * kk + 16 * l4) ^ vkey));
                    o[f] = __builtin_amdgcn_mfma_f32_16x16x32_bf16(pa, vb, o[f], 0, 0, 0);
                }
            }
            __builtin_amdgcn_s_setprio(0);
            __syncthreads();
            ck0 = a; ck1 = b; cv0 = c; cv1 = d;
        }
    }
    // ---- final row-sum reduce (per-lane partials -> row totals)
    l_run += __shfl_xor(l_run, 16);
    l_run += __shfl_xor(l_run, 32);
    // ---- output: o[f][r] is row q = wid*16 + 4*l4 + r; its l_run lives at lane 4*l4+r
#pragma unroll
    for (int r = 0; r < 4; r++) {
        float lr = __shfl(l_run, 4 * l4 + r);
        float inv = 1.f / lr;
        int qa = q0 + wid * 16 + l4 * 4 + r;
        u16* dst = ctx + (size_t)(bb * 2048 + qa) * 1024 + hh * 64;
#pragma unroll
        for (int f = 0; f < 4; f++) dst[f * 16 + l15] = f2bf(o[f][r] * inv);
    }
}

// ----------------------------------------------------------------
extern "C" void kernel_launch(void* const* d_in, const int* in_sizes, int n_in,
                              void* d_out, int out_size, void* d_ws, size_t ws_size,
                              hipStream_t stream)
{
    const float* x    = (const float*)d_in[0];
    const float* ln_g = (const float*)d_in[1];
    const float* ln_b = (const float*)d_in[2];
    const float* wqkv = (const float*)d_in[3];
    const float* bqkv = (const float*)d_in[4];
    const float* wo   = (const float*)d_in[5];
    const float* bo   = (const float*)d_in[6];
    float* out = (float*)d_out;

    char* ws = (char*)d_ws;
    u16* hbuf  = (u16*)ws;                          // 8 MB   (LN out; later woT reuses front)
    u16* qkvb  = (u16*)(ws + 8388608);              // 24 MB  q/k head-major, v transposed
    u16* ctxb  = (u16*)(ws + 33554432);             // 8 MB   (wqkvT first, then ctx)
    u16* wqkvT = ctxb;                              // 6.29 MB (dead before attn writes ctx)
    u16* woT   = hbuf;                              // 2 MB   (hbuf dead after qkv_gemm)

    transpose_f32_bf16<<<dim3(48, 16), 256, 0, stream>>>(wqkv, wqkvT, 1024, 3072);
    ln_kernel<<<4096, 256, 0, stream>>>(x, ln_g, ln_b, hbuf);
    qkv_gemm128<<<dim3(24, 32), 256, 0, stream>>>(hbuf, wqkvT, bqkv, qkvb);
    transpose_f32_bf16<<<dim3(16, 16), 256, 0, stream>>>(wo, woT, 1024, 1024);
    attn_kernel<<<1024, 256, 0, stream>>>(
        qkvb, qkvb + QKV_SZ, qkvb + 2 * QKV_SZ, ctxb);
    out_gemm128<<<dim3(8, 32), 256, 0, stream>>>(ctxb, woT, bo, x, out);
}